// Round 2
// baseline (6414.880 us; speedup 1.0000x reference)
//
#include <hip/hip_runtime.h>
#include <hip/hip_bf16.h>

#define B_   16
#define T_   32
#define N_   512
#define C_   128
#define H_   128
#define HL_  512
#define G4_  2048
#define D_   65536
#define BT_  512
#define TNH_ 2097152   // T*N*H
#define EPS_ 1e-5f

static __device__ __forceinline__ float sigmoidf_(float x) {
  return 1.f / (1.f + __expf(-x));
}

// ---------------- degree + normalized adjacency ----------------
__global__ void k_deg(const float* __restrict__ adj, float* __restrict__ dv) {
  int i = blockIdx.x;
  int lane = threadIdx.x;              // 64
  const float* row = adj + (long)i * N_;
  float s = 0.f;
  for (int j = lane; j < N_; j += 64) s += row[j];
  #pragma unroll
  for (int off = 32; off > 0; off >>= 1) s += __shfl_down(s, off, 64);
  if (lane == 0) dv[i] = rsqrtf(s + 1.f);   // +1 for self-loop
}

__global__ void k_mnorm(const float* __restrict__ adj, const float* __restrict__ dv,
                        float* __restrict__ M) {
  int idx = blockIdx.x * 256 + threadIdx.x;   // 262144
  int i = idx >> 9, j = idx & (N_ - 1);
  float a = adj[idx] + ((i == j) ? 1.f : 0.f);
  M[idx] = dv[i] * a * dv[j];
}

// ---------------- tiled fp32 GEMM (NN): C[bt] = A[bt] * B[bt/t] ----------------
// BM=BN=128, BK=16; 256 threads; each thread 8x8.
// NOTE: out may alias A (in-place row-wise GEMM): each block reads only its own
// 128 rows during the K loop and writes them only in the epilogue, so no
// cross-block or read-after-write hazard exists. Hence NO __restrict__ here.
#define GBM 128
#define GBN 128
#define GBK 16

__global__ __launch_bounds__(256, 2)
void k_gemm_nn(float* out,
               const float* A, long aStrideBT, int lda,
               const float* __restrict__ Bsrc, long bStrideBT, long bStrideT,
               const float* __restrict__ bias,   // per-t bias[t*H_] or nullptr
               int K)
{
  __shared__ float As[GBK][GBM + 4];
  __shared__ float Bs[GBK][GBN + 4];
  int mt = blockIdx.x;
  int bt = blockIdx.y;
  int t  = bt & (T_ - 1);
  const float* Ap = A + (long)bt * aStrideBT + (long)mt * GBM * lda;
  const float* Bp = Bsrc + (long)bt * bStrideBT + (long)t * bStrideT;
  float* Cp = out + ((long)bt * N_ + (long)mt * GBM) * H_;

  int tid = threadIdx.x;
  int tx = tid & 15, ty = tid >> 4;
  int am = tid >> 1, ak = (tid & 1) * 8;       // A stage: row am, k-offset ak
  int br = tid >> 4, bc = (tid & 15) * 8;      // B stage: row br, col bc

  float acc[8][8];
  #pragma unroll
  for (int i = 0; i < 8; ++i)
    #pragma unroll
    for (int j = 0; j < 8; ++j) acc[i][j] = 0.f;

  for (int k0 = 0; k0 < K; k0 += GBK) {
    float4 a0 = *(const float4*)(Ap + (long)am * lda + k0 + ak);
    float4 a1 = *(const float4*)(Ap + (long)am * lda + k0 + ak + 4);
    float4 b0 = *(const float4*)(Bp + (long)(k0 + br) * H_ + bc);
    float4 b1 = *(const float4*)(Bp + (long)(k0 + br) * H_ + bc + 4);
    As[ak+0][am] = a0.x; As[ak+1][am] = a0.y; As[ak+2][am] = a0.z; As[ak+3][am] = a0.w;
    As[ak+4][am] = a1.x; As[ak+5][am] = a1.y; As[ak+6][am] = a1.z; As[ak+7][am] = a1.w;
    *(float4*)&Bs[br][bc]     = b0;
    *(float4*)&Bs[br][bc + 4] = b1;
    __syncthreads();
    #pragma unroll
    for (int kk = 0; kk < GBK; ++kk) {
      float a[8], b[8];
      *(float4*)&a[0] = *(const float4*)&As[kk][ty * 8];
      *(float4*)&a[4] = *(const float4*)&As[kk][ty * 8 + 4];
      *(float4*)&b[0] = *(const float4*)&Bs[kk][tx * 8];
      *(float4*)&b[4] = *(const float4*)&Bs[kk][tx * 8 + 4];
      #pragma unroll
      for (int i = 0; i < 8; ++i)
        #pragma unroll
        for (int j = 0; j < 8; ++j)
          acc[i][j] = fmaf(a[i], b[j], acc[i][j]);
    }
    __syncthreads();
  }
  float bv[8] = {0,0,0,0,0,0,0,0};
  if (bias) {
    const float* bp2 = bias + (long)t * H_ + tx * 8;
    #pragma unroll
    for (int j = 0; j < 8; ++j) bv[j] = bp2[j];
  }
  #pragma unroll
  for (int i = 0; i < 8; ++i) {
    float* dst = Cp + (long)(ty * 8 + i) * H_ + tx * 8;
    float4 r0 = make_float4(acc[i][0]+bv[0], acc[i][1]+bv[1], acc[i][2]+bv[2], acc[i][3]+bv[3]);
    float4 r1 = make_float4(acc[i][4]+bv[4], acc[i][5]+bv[5], acc[i][6]+bv[6], acc[i][7]+bv[7]);
    *(float4*)dst       = r0;
    *(float4*)(dst + 4) = r1;
  }
}

// ---------------- NT GEMM, deterministic split-K (partials, no atomics) ------
// part[kc][512][2048] = A[512][K]~chunk kc  *  B[2048][K]^T~chunk kc
__global__ __launch_bounds__(256, 2)
void k_gemm_nt_splitk(float* __restrict__ part,
                      const float* __restrict__ A, int lda,
                      const float* __restrict__ Bt, int ldb,
                      int Kchunk)
{
  __shared__ float As[GBK][GBM + 4];
  __shared__ float Bs[GBK][GBN + 4];
  int bx = blockIdx.x;
  int mt = bx & 3;           // 512/128
  int nt = (bx >> 2) & 15;   // 2048/128
  int kc = bx >> 6;
  const float* Ap = A  + (long)mt * GBM * lda + (long)kc * Kchunk;
  const float* Bp = Bt + (long)nt * GBN * ldb + (long)kc * Kchunk;

  int tid = threadIdx.x;
  int tx = tid & 15, ty = tid >> 4;
  int am = tid >> 1, ak = (tid & 1) * 8;

  float acc[8][8];
  #pragma unroll
  for (int i = 0; i < 8; ++i)
    #pragma unroll
    for (int j = 0; j < 8; ++j) acc[i][j] = 0.f;

  for (int k0 = 0; k0 < Kchunk; k0 += GBK) {
    float4 a0 = *(const float4*)(Ap + (long)am * lda + k0 + ak);
    float4 a1 = *(const float4*)(Ap + (long)am * lda + k0 + ak + 4);
    float4 b0 = *(const float4*)(Bp + (long)am * ldb + k0 + ak);
    float4 b1 = *(const float4*)(Bp + (long)am * ldb + k0 + ak + 4);
    As[ak+0][am] = a0.x; As[ak+1][am] = a0.y; As[ak+2][am] = a0.z; As[ak+3][am] = a0.w;
    As[ak+4][am] = a1.x; As[ak+5][am] = a1.y; As[ak+6][am] = a1.z; As[ak+7][am] = a1.w;
    Bs[ak+0][am] = b0.x; Bs[ak+1][am] = b0.y; Bs[ak+2][am] = b0.z; Bs[ak+3][am] = b0.w;
    Bs[ak+4][am] = b1.x; Bs[ak+5][am] = b1.y; Bs[ak+6][am] = b1.z; Bs[ak+7][am] = b1.w;
    __syncthreads();
    #pragma unroll
    for (int kk = 0; kk < GBK; ++kk) {
      float a[8], b[8];
      *(float4*)&a[0] = *(const float4*)&As[kk][ty * 8];
      *(float4*)&a[4] = *(const float4*)&As[kk][ty * 8 + 4];
      *(float4*)&b[0] = *(const float4*)&Bs[kk][tx * 8];
      *(float4*)&b[4] = *(const float4*)&Bs[kk][tx * 8 + 4];
      #pragma unroll
      for (int i = 0; i < 8; ++i)
        #pragma unroll
        for (int j = 0; j < 8; ++j)
          acc[i][j] = fmaf(a[i], b[j], acc[i][j]);
    }
    __syncthreads();
  }
  float* base = part + (long)kc * (BT_ * G4_);
  #pragma unroll
  for (int i = 0; i < 8; ++i) {
    float* dst = base + (long)(mt * GBM + ty * 8 + i) * G4_ + nt * GBN + tx * 8;
    float4 r0 = make_float4(acc[i][0], acc[i][1], acc[i][2], acc[i][3]);
    float4 r1 = make_float4(acc[i][4], acc[i][5], acc[i][6], acc[i][7]);
    *(float4*)dst       = r0;
    *(float4*)(dst + 4) = r1;
  }
}

__global__ void k_reduce_gates(float* __restrict__ G, const float* __restrict__ part,
                               const float* __restrict__ b1, const float* __restrict__ b2) {
  int idx = blockIdx.x * 256 + threadIdx.x;   // 512*2048
  int g = idx & (G4_ - 1);
  float s = b1[g] + b2[g];
  #pragma unroll
  for (int p = 0; p < 4; ++p) s += part[(long)p * (BT_ * G4_) + idx];
  G[idx] = s;
}

// ---------------- GraphNorm (+ residual + ReLU), stats over B=16 ----------------
// out may alias pre (read-complete-before-write per thread; threads own disjoint idx).
__global__ __launch_bounds__(256)
void k_graphnorm(float* out, const float* pre, const float* resid,
                 const float* __restrict__ wgt, const float* __restrict__ bias,
                 const float* __restrict__ ms)
{
  int idx = blockIdx.x * 256 + threadIdx.x;   // over T*N*H
  int h = idx & 127;
  float v[16];
  float mean = 0.f;
  #pragma unroll
  for (int bb = 0; bb < 16; ++bb) { v[bb] = pre[(long)bb * TNH_ + idx]; mean += v[bb]; }
  mean *= (1.f / 16.f);
  float msh = ms[h];
  float var = 0.f;
  #pragma unroll
  for (int bb = 0; bb < 16; ++bb) { v[bb] -= msh * mean; var += v[bb] * v[bb]; }
  var *= (1.f / 16.f);
  float sc = wgt[h] * rsqrtf(var + EPS_);
  float bh = bias[h];
  #pragma unroll
  for (int bb = 0; bb < 16; ++bb) {
    float r = sc * v[bb] + bh + resid[(long)bb * TNH_ + idx];
    out[(long)bb * TNH_ + idx] = fmaxf(r, 0.f);
  }
}

// ---------------- LSTM helpers ----------------
__global__ void k_transpose_whh(const float* __restrict__ W, float* __restrict__ WT) {
  int idx = blockIdx.x * 256 + threadIdx.x;   // 512*2048
  int k = idx >> 11, g = idx & (G4_ - 1);
  WT[idx] = W[(long)g * HL_ + k];             // WT[k][g] = W[g][k]
}

__global__ __launch_bounds__(128)
void k_lstm_step(const float* __restrict__ G, const float* __restrict__ WT,
                 float* __restrict__ y, float* __restrict__ cbuf, int t)
{
  __shared__ float hs[HL_];
  int b = blockIdx.x, ch = blockIdx.y;
  int tid = threadIdx.x;
  int j = ch * 128 + tid;
  if (t == 0) {
    #pragma unroll
    for (int q = 0; q < 4; ++q) hs[q * 128 + tid] = 0.f;
  } else {
    const float* hp = y + ((long)b * T_ + (t - 1)) * HL_;
    #pragma unroll
    for (int q = 0; q < 4; ++q) hs[q * 128 + tid] = hp[q * 128 + tid];
  }
  __syncthreads();
  const float* g0 = G + ((long)b * T_ + t) * G4_;
  float ai = g0[j], af = g0[HL_ + j], ag = g0[2 * HL_ + j], ao = g0[3 * HL_ + j];
  const float* W = WT + j;
  #pragma unroll 8
  for (int k = 0; k < HL_; ++k) {
    float hk = hs[k];
    const float* wr = W + (long)k * G4_;
    ai = fmaf(hk, wr[0],        ai);
    af = fmaf(hk, wr[HL_],      af);
    ag = fmaf(hk, wr[2 * HL_],  ag);
    ao = fmaf(hk, wr[3 * HL_],  ao);
  }
  float cp = (t == 0) ? 0.f : cbuf[b * HL_ + j];
  float iv = sigmoidf_(ai), fv = sigmoidf_(af), ov = sigmoidf_(ao);
  float gv = tanhf(ag);
  float c = fv * cp + iv * gv;
  float h = ov * tanhf(c);
  cbuf[b * HL_ + j] = c;
  y[((long)b * T_ + t) * HL_ + j] = h;
}

__global__ void k_final(const float* __restrict__ y1, const float* __restrict__ Wp,
                        const float* __restrict__ bp, float* __restrict__ out) {
  int tid = threadIdx.x;      // 128 = 16 b * 8 o
  int b = tid >> 3, o = tid & 7;
  const float* h = y1 + ((long)b * T_ + (T_ - 1)) * HL_;
  const float* w = Wp + (long)o * HL_;
  float s = bp[o];
  for (int k = 0; k < HL_; ++k) s = fmaf(h[k], w[k], s);
  out[b * 8 + o] = s;
}

// ---------------- launch ----------------
extern "C" void kernel_launch(void* const* d_in, const int* in_sizes, int n_in,
                              void* d_out, int out_size, void* d_ws, size_t ws_size,
                              hipStream_t stream)
{
  const float* x    = (const float*)d_in[0];
  const float* adj  = (const float*)d_in[1];
  const float* W1   = (const float*)d_in[2];
  const float* b1   = (const float*)d_in[3];
  const float* W2   = (const float*)d_in[4];
  const float* b2   = (const float*)d_in[5];
  const float* gn1w = (const float*)d_in[6];
  const float* gn1b = (const float*)d_in[7];
  const float* gn1m = (const float*)d_in[8];
  const float* gn2w = (const float*)d_in[9];
  const float* gn2b = (const float*)d_in[10];
  const float* gn2m = (const float*)d_in[11];
  const float* Wih0 = (const float*)d_in[12];
  const float* Whh0 = (const float*)d_in[13];
  const float* bih0 = (const float*)d_in[14];
  const float* bhh0 = (const float*)d_in[15];
  const float* Wih1 = (const float*)d_in[16];
  const float* Whh1 = (const float*)d_in[17];
  const float* bih1 = (const float*)d_in[18];
  const float* bhh1 = (const float*)d_in[19];
  const float* Wp   = (const float*)d_in[20];
  const float* bp   = (const float*)d_in[21];
  float* out = (float*)d_out;

  // -------- workspace layout: 70,009,344 floats = 280.0 MB total --------
  // (round-0 evidence: ws_size >= 288.4 MB, so this fits; d_in is NEVER used
  //  as scratch — that was round-0's post-timing-divergence bug)
  float* w = (float*)d_ws;
  float* Mn  = w; w += 262144;    // [N][N]
  float* dv  = w; w += 512;
  float* G0  = w; w += 1048576;   // [BT][2048]
  float* G1  = w; w += 1048576;
  float* y0  = w; w += 262144;    // [B][T][HL]
  float* y1  = w; w += 262144;
  float* c0  = w; w += 8192;      // [B][HL]
  float* c1  = w; w += 8192;
  float* P   = w; w += 33554432;  // [B][T][N][H]
  float* Q   = w; w += 33554432;  // [B][T][N][H]
  // After the GCN stack completes, P (h1) is dead; reuse its space for LSTM prep:
  float* Gp  = P;                 // [4][512][2048] split-K partials (16 MB)
  float* WT0 = P + 4194304;       // [512][2048]
  float* WT1 = P + 5242880;       // [512][2048]

  // graph prep
  k_deg<<<N_, 64, 0, stream>>>(adj, dv);
  k_mnorm<<<1024, 256, 0, stream>>>(adj, dv, Mn);

  // GCN layer 1 (reassociated: M@(X@W) == (M@X)@W):
  //   agg1 = M @ x -> P ; pre1 = agg1 @ W1[t] + b1[t] (IN PLACE in P)
  //   h1 = relu(GN(pre1) + x) (IN PLACE in P)
  k_gemm_nn<<<dim3(4, BT_), 256, 0, stream>>>(P, Mn, 0L, N_, x, (long)N_*C_, 0L, nullptr, N_);
  k_gemm_nn<<<dim3(4, BT_), 256, 0, stream>>>(P, P, (long)N_*H_, C_, W1, 0L, (long)C_*H_, b1, C_);
  k_graphnorm<<<8192, 256, 0, stream>>>(P, P, x, gn1w, gn1b, gn1m);

  // GCN layer 2: agg2 = M @ h1 -> Q ; pre2 = agg2 @ W2[t] + b2[t] (in place in Q)
  //   h2 = relu(GN(pre2) + h1) (in place in Q)
  k_gemm_nn<<<dim3(4, BT_), 256, 0, stream>>>(Q, Mn, 0L, N_, P, (long)N_*H_, 0L, nullptr, N_);
  k_gemm_nn<<<dim3(4, BT_), 256, 0, stream>>>(Q, Q, (long)N_*H_, H_, W2, 0L, (long)H_*H_, b2, H_);
  k_graphnorm<<<8192, 256, 0, stream>>>(Q, Q, P, gn2w, gn2b, gn2m);
  // ---- P is now dead; Gp/WT0/WT1 live in its space from here on ----

  k_transpose_whh<<<4096, 256, 0, stream>>>(Whh0, WT0);
  k_transpose_whh<<<4096, 256, 0, stream>>>(Whh1, WT1);

  // LSTM layer 0: input projection (deterministic split-K x4) + 32 recurrent steps
  k_gemm_nt_splitk<<<256, 256, 0, stream>>>(Gp, Q, D_, Wih0, D_, D_ / 4);
  k_reduce_gates<<<4096, 256, 0, stream>>>(G0, Gp, bih0, bhh0);
  for (int t = 0; t < T_; ++t)
    k_lstm_step<<<dim3(16, 4), 128, 0, stream>>>(G0, WT0, y0, c0, t);

  // LSTM layer 1
  k_gemm_nt_splitk<<<256, 256, 0, stream>>>(Gp, y0, HL_, Wih1, HL_, HL_ / 4);
  k_reduce_gates<<<4096, 256, 0, stream>>>(G1, Gp, bih1, bhh1);
  for (int t = 0; t < T_; ++t)
    k_lstm_step<<<dim3(16, 4), 128, 0, stream>>>(G1, WT1, y1, c1, t);

  k_final<<<1, 128, 0, stream>>>(y1, Wp, bp, out);
}